// Round 1
// baseline (37768.433 us; speedup 1.0000x reference)
//
#include <hip/hip_runtime.h>
#include <math.h>

// Glacier SIA time-stepper, 512x512, 400 steps, persistent single kernel with
// hand-rolled grid barrier (monotonic counter). 256 blocks x 256 threads:
// co-residency guaranteed (<=1 block/CU), so the barrier cannot deadlock.
//
// ws layout (bytes):
//   [0]      unsigned barrier counter
//   [64]     unsigned gmax[400] (per-step max-D slots, float bits, all D>0)
//   [4096]   float Ha[512*512]   (H ping)
//   [+1MB]   float Hb[512*512]   (H pong)
//   [+2MB]   float smb[512*512]
//   [+3MB]   float D[511*511]
// First 4096 bytes are zeroed by a captured hipMemsetAsync each call.

#define NN 512
#define MM (NN * NN)
#define ND 511
#define NSTEPS 400
#define NBLK 256

__device__ __forceinline__ void gsync(unsigned* cnt, unsigned target) {
  __threadfence();                    // release (agent scope)
  __syncthreads();
  if (threadIdx.x == 0) {
    __hip_atomic_fetch_add(cnt, 1u, __ATOMIC_RELEASE, __HIP_MEMORY_SCOPE_AGENT);
    while (__hip_atomic_load(cnt, __ATOMIC_ACQUIRE, __HIP_MEMORY_SCOPE_AGENT) < target)
      __builtin_amdgcn_s_sleep(4);
  }
  __syncthreads();
  __threadfence();                    // acquire (invalidate caches)
}

__global__ __launch_bounds__(256)
void glacier_kernel(const float* __restrict__ Zt,
                    const float* __restrict__ precip,
                    const float* __restrict__ Tm,
                    const float* __restrict__ Ts,
                    float* __restrict__ out,       // [3*MM]: H1, H2, H
                    unsigned* __restrict__ cnt,
                    unsigned* __restrict__ gmaxu,
                    float* __restrict__ Ha,
                    float* __restrict__ Hb,
                    float* __restrict__ smb,
                    float* __restrict__ Dar) {
  const int tx = threadIdx.x;
  unsigned bar = 0;
  const float TmTs = Tm[0] + Ts[0];
  // FD * (RHO*G)^3 folded in double, cast to f32 (mirrors XLA constant fold)
  const double RG = 910.0 * 9.81;
  const float CDIF = (float)(1e-16 * RG * RG * RG);

  // ---- init: H=0 (both buffers), smb from precip[0] & Zs=Ztopo, zero H1/H2 out
  for (int r = blockIdx.x; r < NN; r += NBLK) {
    for (int cc = 0; cc < 2; ++cc) {
      int c = tx + cc * 256;
      if (c < NN) {
        int id = r * NN + c;
        Ha[id] = 0.f;
        Hb[id] = 0.f;
        float T = TmTs - 0.006f * Zt[id];
        smb[id] = precip[id] - 0.5f * fmaxf(T, 0.f);
        out[id] = 0.f;
        out[MM + id] = 0.f;
      }
    }
  }
  bar += NBLK; gsync(cnt, bar);

  float time = 0.f, t_last = 0.f;
  int idx = 0;
  bool s1 = false, s2 = false;
  float* Hc = Ha;
  float* Hn = Hb;

  __shared__ float wmax[4];

  for (int k = 0; k < NSTEPS; ++k) {
    if (time >= 200.0f) break;  // == reference's active-freeze (uniform)

    // ---- phase A: D on staggered (511x511) grid + global max
    float lmax = 0.f;
    for (int r = blockIdx.x; r < ND; r += NBLK) {
      const float* Hr0 = Hc + r * NN;
      const float* Hr1 = Hr0 + NN;
      const float* Zr0 = Zt + r * NN;
      const float* Zr1 = Zr0 + NN;
      for (int cc = 0; cc < 2; ++cc) {
        int c = tx + cc * 256;
        if (c < ND) {
          float h00 = Hr0[c], h01 = Hr0[c + 1], h10 = Hr1[c], h11 = Hr1[c + 1];
          float z00 = Zr0[c] + h00, z01 = Zr0[c + 1] + h01;
          float z10 = Zr1[c] + h10, z11 = Zr1[c + 1] + h11;
          float havg = 0.25f * (((h00 + h11) + h01) + h10);
          float sx = 0.5f * ((z01 - z00) / 200.f + (z11 - z10) / 200.f);
          float sy = 0.5f * ((z10 - z00) / 200.f + (z11 - z01) / 200.f);
          float sn = sqrtf((sx * sx + sy * sy) + 1e-10f);
          float h2 = havg * havg;
          float h4 = h2 * h2;
          float h5 = h4 * havg;
          float d = CDIF * h5 * (sn * sn) + 1e-10f;
          Dar[r * ND + c] = d;
          lmax = fmaxf(lmax, d);
        }
      }
    }
    // block reduce max (all D > 0, so float-bits compare as uint works)
    for (int off = 32; off; off >>= 1) lmax = fmaxf(lmax, __shfl_xor(lmax, off));
    if ((tx & 63) == 0) wmax[tx >> 6] = lmax;
    __syncthreads();
    if (tx == 0) {
      float bm = fmaxf(fmaxf(wmax[0], wmax[1]), fmaxf(wmax[2], wmax[3]));
      atomicMax(gmaxu + k, __float_as_uint(bm));
    }
    bar += NBLK; gsync(cnt, bar);

    float maxD = __uint_as_float(gmaxu[k]);
    float dt = fminf(40000.0f / (2.7f * maxD), 1.0f);
    float tnew = time + dt;
    bool cap1 = (!s1) && (tnew >= 120.0f);
    bool cap2 = (!s2) && (tnew >= 160.0f);
    bool do_upd = (tnew - t_last) >= 5.0f;
    int idx_new = do_upd ? min(idx + 1, 63) : idx;
    const float* prow = precip + (size_t)idx_new * MM;

    // ---- phase B: fluxes + H update (interior 510x510), fused captures/smb
    for (int a = blockIdx.x; a < NN - 2; a += NBLK) {
      int i = a + 1;
      const float* D0 = Dar + a * ND;
      const float* D1 = D0 + ND;
      for (int cc = 0; cc < 2; ++cc) {
        int b = tx + cc * 256;
        if (b < NN - 2) {
          int j = b + 1;
          int id = i * NN + j;
          float d00 = D0[b], d01 = D0[b + 1], d10 = D1[b], d11 = D1[b + 1];
          float hC = Hc[id];
          float zc = Zt[id] + hC;
          float zw = Zt[id - 1] + Hc[id - 1];
          float ze = Zt[id + 1] + Hc[id + 1];
          float zn = Zt[id - NN] + Hc[id - NN];
          float zs = Zt[id + NN] + Hc[id + NN];
          float qx0 = -(0.5f * (d00 + d10)) * (zc - zw) / 200.f;
          float qx1 = -(0.5f * (d01 + d11)) * (ze - zc) / 200.f;
          float qy0 = -(0.5f * (d00 + d01)) * (zc - zn) / 200.f;
          float qy1 = -(0.5f * (d10 + d11)) * (zs - zc) / 200.f;
          float dHdt = -((qx1 - qx0) / 200.f + (qy1 - qy0) / 200.f);
          float hnew = fmaxf(hC + dt * (dHdt + smb[id]), 0.f);
          Hn[id] = hnew;
          if (cap1) out[id] = hnew;
          if (cap2) out[MM + id] = hnew;
          if (do_upd) {
            float T = TmTs - 0.006f * (Zt[id] + hnew);
            smb[id] = prow[id] - 0.5f * fmaxf(T, 0.f);
          }
        }
      }
    }
    time = tnew;
    s1 = s1 || cap1;
    s2 = s2 || cap2;
    if (do_upd) { idx = idx_new; t_last = tnew; }
    float* tmp = Hc; Hc = Hn; Hn = tmp;
    bar += NBLK; gsync(cnt, bar);
  }

  // ---- final H (boundaries are 0 from init; interior from last step)
  for (int r = blockIdx.x; r < NN; r += NBLK) {
    for (int cc = 0; cc < 2; ++cc) {
      int c = tx + cc * 256;
      if (c < NN) out[2 * MM + r * NN + c] = Hc[r * NN + c];
    }
  }
}

extern "C" void kernel_launch(void* const* d_in, const int* in_sizes, int n_in,
                              void* d_out, int out_size, void* d_ws, size_t ws_size,
                              hipStream_t stream) {
  const float* Zt = (const float*)d_in[0];
  const float* precip = (const float*)d_in[1];
  const float* Tm = (const float*)d_in[2];
  const float* Ts = (const float*)d_in[3];
  float* out = (float*)d_out;

  unsigned* cnt = (unsigned*)d_ws;
  unsigned* gmaxu = cnt + 16;                      // offset 64 B
  float* Ha = (float*)((char*)d_ws + 4096);
  float* Hb = Ha + MM;
  float* smb = Hb + MM;
  float* Dar = smb + MM;                           // 511*511 floats

  // reset barrier counter + per-step max slots (ws not re-poisoned by harness)
  hipMemsetAsync(d_ws, 0, 4096, stream);
  glacier_kernel<<<NBLK, 256, 0, stream>>>(Zt, precip, Tm, Ts, out,
                                           cnt, gmaxu, Ha, Hb, smb, Dar);
}

// Round 2
// 22423.486 us; speedup vs baseline: 1.6843x; 1.6843x over previous
//
#include <hip/hip_runtime.h>
#include <math.h>

// Glacier SIA stepper. 128 persistent blocks x 512 threads (thread = column).
// One grid barrier per step. Per-block band: 4 owned rows; computes H on 6
// rows and D on 5 rows redundantly so neighbors only exchange halo rows.
// smb is register-private (no spatial coupling). Zs/D/Hn bands persist in LDS.
//
// ws layout (bytes):
//   0    : unsigned cnt            (arrival counter)
//   128  : unsigned epochs[16]     (stride 128 B, release broadcast lines)
//   2560 : unsigned gmax[401]      (per-step max-D, float bits)
//   8192 : float Ha[512*512], Hb, Da, Db   (published-row ping-pong buffers)
// First 8192 B zeroed by a captured hipMemsetAsync each call.

#define NN 512
#define MM (NN * NN)
#define NSTEPS 400
#define NBLK 128
#define HR 4              // owned rows per block
#define TPB 512

__device__ __forceinline__ void gsync(unsigned* cnt, unsigned* epochs,
                                      unsigned epoch, unsigned target) {
  __threadfence();
  __syncthreads();
  if (threadIdx.x == 0) {
    __hip_atomic_fetch_add(cnt, 1u, __ATOMIC_RELEASE, __HIP_MEMORY_SCOPE_AGENT);
    if (blockIdx.x == 0) {
      while (__hip_atomic_load(cnt, __ATOMIC_ACQUIRE, __HIP_MEMORY_SCOPE_AGENT) < target)
        __builtin_amdgcn_s_sleep(2);
#pragma unroll
      for (int g = 0; g < 16; ++g)
        __hip_atomic_store(epochs + g * 32, epoch, __ATOMIC_RELEASE, __HIP_MEMORY_SCOPE_AGENT);
    } else {
      unsigned* ep = epochs + ((blockIdx.x >> 3) * 32);
      while (__hip_atomic_load(ep, __ATOMIC_ACQUIRE, __HIP_MEMORY_SCOPE_AGENT) < epoch)
        __builtin_amdgcn_s_sleep(2);
    }
  }
  __syncthreads();
  __threadfence();
}

__global__ __launch_bounds__(TPB)
void glacier_kernel(const float* __restrict__ Zt,
                    const float* __restrict__ precip,
                    const float* __restrict__ Tm,
                    const float* __restrict__ Ts,
                    float* __restrict__ out,        // [3*MM]: H1, H2, H
                    unsigned* __restrict__ cnt,
                    unsigned* __restrict__ epochs,
                    unsigned* __restrict__ gmaxu,
                    float* __restrict__ Ha, float* __restrict__ Hb,
                    float* __restrict__ Da, float* __restrict__ Db) {
  const int j = threadIdx.x;           // column 0..511
  const int a = blockIdx.x * HR;       // first owned row
  const float TmTs = Tm[0] + Ts[0];
  const double RG = 910.0 * 9.81;
  const float CDIF = (float)(1e-16 * RG * RG * RG);

  __shared__ float Zs2[2][HR + 4][NN]; // Zs rows a-2 .. a+5, ping-pong
  __shared__ float DB[HR + 3][NN];     // D  rows a-2 .. a+4 (in-place update)
  __shared__ float HnB[HR + 2][NN];    // new H rows a-1 .. a+4 (intra-step)
  __shared__ float wmax[TPB / 64];

  float ztreg[HR + 4];                 // Zt rows a-2 .. a+5 (column j)
  float hcur[HR + 2];                  // H rows a-1 .. a+4
  float smbreg[HR + 2];                // smb rows a-1 .. a+4 (private!)

  // ---------------- prologue (no cross-block deps; no barrier needed) ------
#pragma unroll
  for (int ls = 0; ls < HR + 4; ++ls) {
    int r = a - 2 + ls;
    float zt = (r >= 0 && r < NN) ? Zt[r * NN + j] : 0.f;
    ztreg[ls] = zt;
    Zs2[0][ls][j] = zt;                // H = 0
  }
#pragma unroll
  for (int ln = 0; ln < HR + 2; ++ln) {
    int r = a - 1 + ln;
    hcur[ln] = 0.f;
    float sm = 0.f;
    if (r >= 0 && r < NN) {
      float T = TmTs - 0.006f * ztreg[ln + 1];
      sm = precip[r * NN + j] - 0.5f * fmaxf(T, 0.f);
    }
    smbreg[ln] = sm;
  }
#pragma unroll
  for (int ld = 0; ld < HR + 3; ++ld) DB[ld][j] = 1e-10f;   // D(H=0) exactly
#pragma unroll
  for (int rr = 0; rr < HR; ++rr) {    // zero H1/H2 (owned rows)
    int id = (a + rr) * NN + j;
    out[id] = 0.f;
    out[MM + id] = 0.f;
  }

  float time = 0.f, t_last = 0.f;
  int idx = 0;
  bool s1 = false, s2 = false;
  unsigned target = 0;

  for (int k = 0; k < NSTEPS; ++k) {
    if (time >= 200.0f) break;         // uniform across blocks (dt identical)

    float maxD = (k == 0) ? 1e-10f
        : __uint_as_float(__hip_atomic_load(gmaxu + k, __ATOMIC_RELAXED,
                                            __HIP_MEMORY_SCOPE_AGENT));
    float dt = fminf(40000.0f / (2.7f * maxD), 1.0f);
    float tnew = time + dt;
    bool cap1 = (!s1) && (tnew >= 120.0f);
    bool cap2 = (!s2) && (tnew >= 160.0f);
    bool do_upd = (tnew - t_last) >= 5.0f;
    int idxn = do_upd ? min(idx + 1, 63) : idx;
    const float* prow = precip + (size_t)idxn * MM;
    const int p = k & 1;
    float* Hwr = (k & 1) ? Ha : Hb;
    const float* Hrd = (k & 1) ? Hb : Ha;
    float* Dwr = (k & 1) ? Da : Db;
    const float* Drd = (k & 1) ? Db : Da;

    // ---- stage halo rows (cross-block data from last step's publishes)
    if (k > 0) {
      if (a - 2 >= 0) {
        Zs2[p][0][j] = ztreg[0] + Hrd[(a - 2) * NN + j];
        DB[0][j] = Drd[(a - 2) * NN + j];
      }
      if (a + 5 < NN)
        Zs2[p][HR + 3][j] = ztreg[HR + 3] + Hrd[(a + 5) * NN + j];
      if (a + 4 < NN - 1)
        DB[HR + 2][j] = Drd[(a + 4) * NN + j];
    }
    __syncthreads();

    // ---- phase 1: new H on rows a-1 .. a+4
    float hnxt[HR + 2];
#pragma unroll
    for (int ln = 0; ln < HR + 2; ++ln) {
      int i = a - 1 + ln;
      if (i >= 0 && i < NN) {
        float hnew = 0.f;
        if (i > 0 && i < NN - 1 && j > 0 && j < NN - 1) {
          int li = ln + 1;
          float zc = Zs2[p][li][j];
          float zw = Zs2[p][li][j - 1];
          float ze = Zs2[p][li][j + 1];
          float zn = Zs2[p][li - 1][j];
          float zs_ = Zs2[p][li + 1][j];
          float d00 = DB[ln][j - 1], d01 = DB[ln][j];
          float d10 = DB[ln + 1][j - 1], d11 = DB[ln + 1][j];
          float qx0 = -(0.5f * (d00 + d10)) * (zc - zw) / 200.f;
          float qx1 = -(0.5f * (d01 + d11)) * (ze - zc) / 200.f;
          float qy0 = -(0.5f * (d00 + d01)) * (zc - zn) / 200.f;
          float qy1 = -(0.5f * (d10 + d11)) * (zs_ - zc) / 200.f;
          float dHdt = -((qx1 - qx0) / 200.f + (qy1 - qy0) / 200.f);
          hnew = fmaxf(hcur[ln] + dt * (dHdt + smbreg[ln]), 0.f);
        }
        float zsn = ztreg[ln + 1] + hnew;
        hnxt[ln] = hnew;
        HnB[ln][j] = hnew;
        Zs2[p ^ 1][ln + 1][j] = zsn;
        if (i == a + 1 || i == a + 2) Hwr[i * NN + j] = hnew;   // publish
        if (i >= a && i < a + HR) {
          int id = i * NN + j;
          if (cap1) out[id] = hnew;
          if (cap2) out[MM + id] = hnew;
        }
        if (do_upd)
          smbreg[ln] = prow[i * NN + j] - 0.5f * fmaxf(TmTs - 0.006f * zsn, 0.f);
      } else {
        hnxt[ln] = 0.f;
      }
    }
    __syncthreads();

    // ---- phase 2: new D on rows a-1 .. a+3 (into DB slots 1..5)
    float lmax = 0.f;
#pragma unroll
    for (int ln = 0; ln < HR + 1; ++ln) {
      int r = a - 1 + ln;
      if (r >= 0 && r < NN - 1 && j < NN - 1) {
        float h00 = HnB[ln][j], h01 = HnB[ln][j + 1];
        float h10 = HnB[ln + 1][j], h11 = HnB[ln + 1][j + 1];
        float z00 = Zs2[p ^ 1][ln + 1][j], z01 = Zs2[p ^ 1][ln + 1][j + 1];
        float z10 = Zs2[p ^ 1][ln + 2][j], z11 = Zs2[p ^ 1][ln + 2][j + 1];
        float havg = 0.25f * (((h00 + h11) + h01) + h10);
        float sx = 0.5f * ((z01 - z00) / 200.f + (z11 - z10) / 200.f);
        float sy = 0.5f * ((z10 - z00) / 200.f + (z11 - z01) / 200.f);
        float sn = sqrtf((sx * sx + sy * sy) + 1e-10f);
        float h2 = havg * havg;
        float h4 = h2 * h2;
        float h5 = h4 * havg;
        float d = CDIF * h5 * (sn * sn) + 1e-10f;
        DB[ln + 1][j] = d;
        if (r == a || r == a + 2) Dwr[r * NN + j] = d;          // publish
        lmax = fmaxf(lmax, d);
      }
    }

    // ---- block max -> global atomicMax (slot k+1)
    for (int off = 32; off; off >>= 1) lmax = fmaxf(lmax, __shfl_xor(lmax, off));
    if ((j & 63) == 0) wmax[j >> 6] = lmax;
    __syncthreads();
    if (j == 0) {
      float bm = wmax[0];
#pragma unroll
      for (int w = 1; w < TPB / 64; ++w) bm = fmaxf(bm, wmax[w]);
      atomicMax(gmaxu + (k + 1), __float_as_uint(bm));
    }

    // ---- bookkeeping + the single barrier
#pragma unroll
    for (int ln = 0; ln < HR + 2; ++ln) hcur[ln] = hnxt[ln];
    time = tnew;
    s1 = s1 || cap1;
    s2 = s2 || cap2;
    if (do_upd) { idx = idxn; t_last = tnew; }
    target += NBLK;
    gsync(cnt, epochs, (unsigned)(k + 1), target);
  }

  // ---- final H (owned rows; hcur slot for row a+rr is rr+1)
#pragma unroll
  for (int rr = 0; rr < HR; ++rr)
    out[2 * MM + (a + rr) * NN + j] = hcur[rr + 1];
}

extern "C" void kernel_launch(void* const* d_in, const int* in_sizes, int n_in,
                              void* d_out, int out_size, void* d_ws, size_t ws_size,
                              hipStream_t stream) {
  const float* Zt = (const float*)d_in[0];
  const float* precip = (const float*)d_in[1];
  const float* Tm = (const float*)d_in[2];
  const float* Ts = (const float*)d_in[3];
  float* out = (float*)d_out;

  unsigned* cnt = (unsigned*)d_ws;
  unsigned* epochs = cnt + 32;                       // byte 128
  unsigned* gmaxu = (unsigned*)((char*)d_ws + 2560); // 401 slots
  float* Ha = (float*)((char*)d_ws + 8192);
  float* Hb = Ha + MM;
  float* Da = Hb + MM;
  float* Db = Da + MM;

  hipMemsetAsync(d_ws, 0, 8192, stream);             // cnt + epochs + gmax
  glacier_kernel<<<NBLK, TPB, 0, stream>>>(Zt, precip, Tm, Ts, out,
                                           cnt, epochs, gmaxu, Ha, Hb, Da, Db);
}

// Round 3
// 15236.282 us; speedup vs baseline: 2.4788x; 1.4717x over previous
//
#include <hip/hip_runtime.h>
#include <math.h>

// Glacier SIA stepper. 129 persistent blocks x 512 threads:
//   block 0            = reducer (gathers per-worker maxD, broadcasts {epoch,maxD})
//   blocks 1..128      = workers, 4 owned rows each (thread = column)
// Sync per step: point-to-point neighbor slot polls + packed broadcast.
// No global barrier, no contended atomics. dt-independent stencil work
// (dHdt) overlaps the global max-reduce.
//
// ws layout (bytes):
//   0     : ull bcast[16]  lines (stride 128 B)  {epoch<<32 | maxD bits}
//   4096  : ull slots[128] lines (stride 128 B)  {epoch<<32 | blockMax bits}
//   32768 : float Ha[MM], Hb[MM], Da[MM], Db[MM] (published-row ping-pong)
// First 20480 B zeroed by captured hipMemsetAsync each call.

#define NN 512
#define MM (NN * NN)
#define NSTEPS 400
#define NW 128            // worker blocks
#define HR 4              // owned rows per worker
#define TPB 512

typedef unsigned long long ull;

__device__ __forceinline__ ull ald(const ull* p) {
  return __hip_atomic_load(p, __ATOMIC_RELAXED, __HIP_MEMORY_SCOPE_AGENT);
}

__global__ __launch_bounds__(TPB)
void glacier_kernel(const float* __restrict__ Zt,
                    const float* __restrict__ precip,
                    const float* __restrict__ Tm,
                    const float* __restrict__ Ts,
                    float* __restrict__ out,        // [3*MM]: H1, H2, H
                    ull* __restrict__ bcast,        // 16 lines, stride 16 ull
                    ull* __restrict__ slots,        // 128 lines, stride 16 ull
                    float* __restrict__ Ha, float* __restrict__ Hb,
                    float* __restrict__ Da, float* __restrict__ Db) {
  const int tx = threadIdx.x;
  __shared__ float Zs2[2][HR + 4][NN];
  __shared__ float DB[HR + 3][NN];
  __shared__ float HnB[HR + 2][NN];
  __shared__ float wmax[TPB / 64];
  __shared__ unsigned sh_max;

  // ======================= reducer block =======================
  if (blockIdx.x == 0) {
    float Tprev = 0.f;      // time before step e-1
    float dtprev = 1.0f;    // dt_0 (maxD=1e-10 clamps to 1.0)
    for (int e = 1; e <= NSTEPS; ++e) {
      if (Tprev >= 200.0f) break;           // step e-1 did not run
      float v = 0.f;
      if (tx < NW) {
        const ull* sp = slots + tx * 16;
        ull s;
        while ((unsigned)((s = ald(sp)) >> 32) < (unsigned)e)
          __builtin_amdgcn_s_sleep(1);
        v = __uint_as_float((unsigned)s);
      }
      for (int off = 32; off; off >>= 1) v = fmaxf(v, __shfl_xor(v, off));
      if ((tx & 63) == 0) wmax[tx >> 6] = v;
      __syncthreads();
      float m = fmaxf(wmax[0], wmax[1]);    // only waves 0,1 hold slots
      if (tx == 0) {
        ull pk = ((ull)(unsigned)e << 32) | __float_as_uint(m);
#pragma unroll
        for (int g = 0; g < 16; ++g)
          __hip_atomic_store(bcast + g * 16, pk, __ATOMIC_RELAXED,
                             __HIP_MEMORY_SCOPE_AGENT);
      }
      __syncthreads();                      // wmax reuse protection
      float Te = Tprev + dtprev;
      dtprev = fminf(40000.0f / (2.7f * m), 1.0f);
      Tprev = Te;
    }
    return;
  }

  // ======================= worker blocks =======================
  const int w = blockIdx.x - 1;
  const int j = tx;                  // column
  const int a = w * HR;              // first owned row
  const float TmTs = Tm[0] + Ts[0];
  const double RG = 910.0 * 9.81;
  const float CDIF = (float)(1e-16 * RG * RG * RG);
  ull* myslot = slots + w * 16;

  float ztreg[HR + 4];
  float hcur[HR + 2];
  float smbreg[HR + 2];

  // ---- prologue (no cross-block deps)
#pragma unroll
  for (int ls = 0; ls < HR + 4; ++ls) {
    int r = a - 2 + ls;
    float zt = (r >= 0 && r < NN) ? Zt[r * NN + j] : 0.f;
    ztreg[ls] = zt;
    Zs2[0][ls][j] = zt;              // H = 0
  }
#pragma unroll
  for (int ln = 0; ln < HR + 2; ++ln) {
    int r = a - 1 + ln;
    hcur[ln] = 0.f;
    float sm = 0.f;
    if (r >= 0 && r < NN) {
      float T = TmTs - 0.006f * ztreg[ln + 1];
      sm = precip[r * NN + j] - 0.5f * fmaxf(T, 0.f);
    }
    smbreg[ln] = sm;
  }
#pragma unroll
  for (int ld = 0; ld < HR + 3; ++ld) DB[ld][j] = 1e-10f;   // D(H=0) exactly
#pragma unroll
  for (int rr = 0; rr < HR; ++rr) {
    int id = (a + rr) * NN + j;
    out[id] = 0.f;
    out[MM + id] = 0.f;
  }

  float time = 0.f, t_last = 0.f;
  int idx = 0;
  bool s1 = false, s2 = false;

  for (int k = 0; k < NSTEPS; ++k) {
    if (time >= 200.0f) break;                 // uniform (dt identical)

    const int p = k & 1;
    float* Hwr = (k & 1) ? Ha : Hb;
    const float* Hrd = (k & 1) ? Hb : Ha;
    float* Dwr = (k & 1) ? Da : Db;
    const float* Drd = (k & 1) ? Db : Da;

    // ---- prefetch precip rows for potential smb update (read-only, safe pre-fence)
    int idxn = min(idx + 1, 63);
    const float* prowN = precip + (size_t)idxn * MM;
    float pf[HR + 2];
#pragma unroll
    for (int ln = 0; ln < HR + 2; ++ln) {
      int i = a - 1 + ln;
      pf[ln] = (i >= 0 && i < NN) ? prowN[i * NN + j] : 0.f;
    }

    // ---- point-to-point neighbor sync (lanes 0,1 poll, same wave)
    if (k > 0 && j < 2) {
      int nb = (j == 0) ? w - 1 : w + 1;
      if (nb >= 0 && nb < NW) {
        const ull* sp = slots + nb * 16;
        while ((unsigned)(ald(sp) >> 32) < (unsigned)k)
          __builtin_amdgcn_s_sleep(1);
      }
    }
    __syncthreads();
    __threadfence();                           // acquire: invalidate caches

    // ---- stage halo rows from neighbors' publishes
    if (k > 0) {
      if (a - 2 >= 0) {
        Zs2[p][0][j] = ztreg[0] + Hrd[(a - 2) * NN + j];
        DB[0][j] = Drd[(a - 2) * NN + j];
      }
      if (a + 5 < NN)
        Zs2[p][HR + 3][j] = ztreg[HR + 3] + Hrd[(a + 5) * NN + j];
      if (a + 4 < NN - 1)
        DB[HR + 2][j] = Drd[(a + 4) * NN + j];
    }
    __syncthreads();

    // ---- part A: dt-independent stencil (overlaps reducer's gather/bcast)
    float dHdt[HR + 2];
#pragma unroll
    for (int ln = 0; ln < HR + 2; ++ln) {
      int i = a - 1 + ln;
      float v = 0.f;
      if (i > 0 && i < NN - 1 && j > 0 && j < NN - 1) {
        int li = ln + 1;
        float zc = Zs2[p][li][j];
        float zw = Zs2[p][li][j - 1];
        float ze = Zs2[p][li][j + 1];
        float zn = Zs2[p][li - 1][j];
        float zs_ = Zs2[p][li + 1][j];
        float d00 = DB[ln][j - 1], d01 = DB[ln][j];
        float d10 = DB[ln + 1][j - 1], d11 = DB[ln + 1][j];
        float qx0 = -(0.5f * (d00 + d10)) * (zc - zw) / 200.f;
        float qx1 = -(0.5f * (d01 + d11)) * (ze - zc) / 200.f;
        float qy0 = -(0.5f * (d00 + d01)) * (zc - zn) / 200.f;
        float qy1 = -(0.5f * (d10 + d11)) * (zs_ - zc) / 200.f;
        v = -((qx1 - qx0) / 200.f + (qy1 - qy0) / 200.f);
      }
      dHdt[ln] = v;
    }

    // ---- get maxD (packed broadcast; payload travels in the atomic itself)
    float maxD;
    if (k == 0) {
      maxD = 1e-10f;
    } else {
      if (j == 0) {
        const ull* bp = bcast + (w >> 3) * 16;
        ull b;
        while ((unsigned)((b = ald(bp)) >> 32) < (unsigned)k)
          __builtin_amdgcn_s_sleep(1);
        sh_max = (unsigned)b;
      }
      __syncthreads();
      maxD = __uint_as_float(sh_max);
    }

    float dt = fminf(40000.0f / (2.7f * maxD), 1.0f);
    float tnew = time + dt;
    bool cap1 = (!s1) && (tnew >= 120.0f);
    bool cap2 = (!s2) && (tnew >= 160.0f);
    bool do_upd = (tnew - t_last) >= 5.0f;

    // ---- part B: finish H update, publishes, captures, smb refresh
    float hnxt[HR + 2];
#pragma unroll
    for (int ln = 0; ln < HR + 2; ++ln) {
      int i = a - 1 + ln;
      float hnew = 0.f;
      if (i >= 0 && i < NN) {
        if (i > 0 && i < NN - 1 && j > 0 && j < NN - 1)
          hnew = fmaxf(hcur[ln] + dt * (dHdt[ln] + smbreg[ln]), 0.f);
        float zsn = ztreg[ln + 1] + hnew;
        HnB[ln][j] = hnew;
        Zs2[p ^ 1][ln + 1][j] = zsn;
        if (i == a + 1 || i == a + 2) Hwr[i * NN + j] = hnew;   // publish H
        if (i >= a && i < a + HR) {
          int id = i * NN + j;
          if (cap1) out[id] = hnew;
          if (cap2) out[MM + id] = hnew;
        }
        if (do_upd)
          smbreg[ln] = pf[ln] - 0.5f * fmaxf(TmTs - 0.006f * zsn, 0.f);
      }
      hnxt[ln] = hnew;
    }
    __syncthreads();

    // ---- phase 2: new D rows a-1..a+3 (into DB slots 1..5) + block max
    float lmax = 0.f;
#pragma unroll
    for (int ln = 0; ln < HR + 1; ++ln) {
      int r = a - 1 + ln;
      if (r >= 0 && r < NN - 1 && j < NN - 1) {
        float h00 = HnB[ln][j], h01 = HnB[ln][j + 1];
        float h10 = HnB[ln + 1][j], h11 = HnB[ln + 1][j + 1];
        float z00 = Zs2[p ^ 1][ln + 1][j], z01 = Zs2[p ^ 1][ln + 1][j + 1];
        float z10 = Zs2[p ^ 1][ln + 2][j], z11 = Zs2[p ^ 1][ln + 2][j + 1];
        float havg = 0.25f * (((h00 + h11) + h01) + h10);
        float sx = 0.5f * ((z01 - z00) / 200.f + (z11 - z10) / 200.f);
        float sy = 0.5f * ((z10 - z00) / 200.f + (z11 - z01) / 200.f);
        float sn = sqrtf((sx * sx + sy * sy) + 1e-10f);
        float h2 = havg * havg;
        float h4 = h2 * h2;
        float h5 = h4 * havg;
        float d = CDIF * h5 * (sn * sn) + 1e-10f;
        DB[ln + 1][j] = d;
        if (r == a || r == a + 2) Dwr[r * NN + j] = d;          // publish D
        lmax = fmaxf(lmax, d);
      }
    }
    for (int off = 32; off; off >>= 1) lmax = fmaxf(lmax, __shfl_xor(lmax, off));
    if ((j & 63) == 0) wmax[j >> 6] = lmax;

    // ---- release my slot: {k+1, blockMax}
    __threadfence();                           // flush my global stores
    __syncthreads();                           // all threads flushed + wmax ready
    if (j == 0) {
      float bm = wmax[0];
#pragma unroll
      for (int q = 1; q < TPB / 64; ++q) bm = fmaxf(bm, wmax[q]);
      ull pk = ((ull)(unsigned)(k + 1) << 32) | __float_as_uint(bm);
      __hip_atomic_store(myslot, pk, __ATOMIC_RELEASE, __HIP_MEMORY_SCOPE_AGENT);
    }

    // ---- bookkeeping
#pragma unroll
    for (int ln = 0; ln < HR + 2; ++ln) hcur[ln] = hnxt[ln];
    time = tnew;
    s1 = s1 || cap1;
    s2 = s2 || cap2;
    if (do_upd) { idx = idxn; t_last = tnew; }
  }

  // ---- final H (owned rows; hcur slot for row a+rr is rr+1)
#pragma unroll
  for (int rr = 0; rr < HR; ++rr)
    out[2 * MM + (a + rr) * NN + j] = hcur[rr + 1];
}

extern "C" void kernel_launch(void* const* d_in, const int* in_sizes, int n_in,
                              void* d_out, int out_size, void* d_ws, size_t ws_size,
                              hipStream_t stream) {
  const float* Zt = (const float*)d_in[0];
  const float* precip = (const float*)d_in[1];
  const float* Tm = (const float*)d_in[2];
  const float* Ts = (const float*)d_in[3];
  float* out = (float*)d_out;

  ull* bcast = (ull*)d_ws;                           // 16 lines @ 128 B
  ull* slots = (ull*)((char*)d_ws + 4096);           // 128 lines @ 128 B
  float* Ha = (float*)((char*)d_ws + 32768);
  float* Hb = Ha + MM;
  float* Da = Hb + MM;
  float* Db = Da + MM;

  hipMemsetAsync(d_ws, 0, 20480, stream);            // bcast + slots
  glacier_kernel<<<NW + 1, TPB, 0, stream>>>(Zt, precip, Tm, Ts, out,
                                             bcast, slots, Ha, Hb, Da, Db);
}

// Round 4
// 2581.024 us; speedup vs baseline: 14.6331x; 5.9032x over previous
//
#include <hip/hip_runtime.h>
#include <math.h>

// Glacier SIA stepper. 129 persistent blocks x 512 threads:
//   block 0 (wave 0 only) = reducer: polls 128 slots, wave-reduces maxD,
//                           scatter-broadcasts {epoch,maxD} to 64 spread lines
//   blocks 1..128         = workers, 4 owned rows each (thread = column)
// NO threadfences: all cross-block data (halo rows, flags) moves via relaxed
// agent-scope atomics (write-through / cache-bypass at MALL). Private state
// (Zt, precip, LDS bands, out) stays cacheable. __syncthreads' vmcnt(0) drain
// orders publishes before the slot release.
//
// ws layout (bytes):
//   0     : ull bcast[64] lines (stride 128 B)  {epoch<<32 | maxD bits}
//   8192  : ull slots[128] lines (stride 128 B) {epoch<<32 | blockMax bits}
//   32768 : float Ha[MM], Hb[MM], Da[MM], Db[MM] (published-row ping-pong)
// First 32768 B zeroed by captured hipMemsetAsync each call.

#define NN 512
#define MM (NN * NN)
#define NSTEPS 400
#define NW 128
#define HR 4
#define TPB 512

typedef unsigned long long ull;

__device__ __forceinline__ ull ald(const ull* p) {
  return __hip_atomic_load(p, __ATOMIC_RELAXED, __HIP_MEMORY_SCOPE_AGENT);
}
__device__ __forceinline__ void asto(ull* p, ull v) {
  __hip_atomic_store(p, v, __ATOMIC_RELAXED, __HIP_MEMORY_SCOPE_AGENT);
}
__device__ __forceinline__ float cload(const float* p) {
  return __hip_atomic_load(p, __ATOMIC_RELAXED, __HIP_MEMORY_SCOPE_AGENT);
}
__device__ __forceinline__ void cstore(float* p, float v) {
  __hip_atomic_store(p, v, __ATOMIC_RELAXED, __HIP_MEMORY_SCOPE_AGENT);
}

__global__ __launch_bounds__(TPB)
void glacier_kernel(const float* __restrict__ Zt,
                    const float* __restrict__ precip,
                    const float* __restrict__ Tm,
                    const float* __restrict__ Ts,
                    float* __restrict__ out,        // [3*MM]: H1, H2, H
                    ull* __restrict__ bcast,        // 64 lines, stride 16 ull
                    ull* __restrict__ slots,        // 128 lines, stride 16 ull
                    float* __restrict__ Ha, float* __restrict__ Hb,
                    float* __restrict__ Da, float* __restrict__ Db) {
  const int tx = threadIdx.x;

  // ======================= reducer (block 0, wave 0) =======================
  if (blockIdx.x == 0) {
    if (tx >= 64) return;
    const int lane = tx;
    const ull* s0 = slots + lane * 16;
    const ull* s1 = slots + (lane + 64) * 16;
    float Tprev = 0.f;      // time before step e-1
    float dtprev = 1.0f;    // dt_0 (maxD=1e-10 clamps to 1.0)
    for (int e = 1; e <= NSTEPS; ++e) {
      if (Tprev >= 200.0f) break;
      ull v0, v1;
      for (;;) {
        v0 = ald(s0); v1 = ald(s1);
        if ((unsigned)(v0 >> 32) >= (unsigned)e &&
            (unsigned)(v1 >> 32) >= (unsigned)e) break;
        __builtin_amdgcn_s_sleep(1);
      }
      float m = fmaxf(__uint_as_float((unsigned)v0),
                      __uint_as_float((unsigned)v1));
      for (int off = 32; off; off >>= 1) m = fmaxf(m, __shfl_xor(m, off));
      ull pk = ((ull)(unsigned)e << 32) | __float_as_uint(m);
      asto(bcast + lane * 16, pk);       // 64 lines in one scatter store
      float Te = Tprev + dtprev;
      dtprev = fminf(40000.0f / (2.7f * m), 1.0f);
      Tprev = Te;
    }
    return;
  }

  // ======================= worker blocks =======================
  __shared__ float Zs2[2][HR + 4][NN];
  __shared__ float DB[HR + 3][NN];
  __shared__ float HnB[HR + 2][NN];
  __shared__ float wmax[TPB / 64];

  const int w = blockIdx.x - 1;
  const int j = tx;                  // column
  const int a = w * HR;              // first owned row
  const float TmTs = Tm[0] + Ts[0];
  const double RG = 910.0 * 9.81;
  const float CDIF = (float)(1e-16 * RG * RG * RG);
  ull* myslot = slots + w * 16;
  const ull* bp = bcast + (w >> 1) * 16;

  float ztreg[HR + 4];
  float hcur[HR + 2];
  float smbreg[HR + 2];

  // ---- prologue (no cross-block deps)
#pragma unroll
  for (int ls = 0; ls < HR + 4; ++ls) {
    int r = a - 2 + ls;
    float zt = (r >= 0 && r < NN) ? Zt[r * NN + j] : 0.f;
    ztreg[ls] = zt;
    Zs2[0][ls][j] = zt;              // H = 0
  }
#pragma unroll
  for (int ln = 0; ln < HR + 2; ++ln) {
    int r = a - 1 + ln;
    hcur[ln] = 0.f;
    float sm = 0.f;
    if (r >= 0 && r < NN) {
      float T = TmTs - 0.006f * ztreg[ln + 1];
      sm = precip[r * NN + j] - 0.5f * fmaxf(T, 0.f);
    }
    smbreg[ln] = sm;
  }
#pragma unroll
  for (int ld = 0; ld < HR + 3; ++ld) DB[ld][j] = 1e-10f;   // D(H=0) exactly
#pragma unroll
  for (int rr = 0; rr < HR; ++rr) {
    int id = (a + rr) * NN + j;
    out[id] = 0.f;
    out[MM + id] = 0.f;
  }

  float time = 0.f, t_last = 0.f;
  int idx = 0;
  bool s1 = false, s2 = false;

  for (int k = 0; k < NSTEPS; ++k) {
    if (time >= 200.0f) break;                 // uniform (dt identical)

    const int p = k & 1;
    float* Hwr = (k & 1) ? Ha : Hb;
    const float* Hrd = (k & 1) ? Hb : Ha;
    float* Dwr = (k & 1) ? Da : Db;
    const float* Drd = (k & 1) ? Db : Da;

    // ---- per-wave neighbor sync + coherent halo staging
    if (k > 0) {
      int lane = j & 63;
      if (lane < 2) {                          // each wave polls both nbrs
        int nb = (lane == 0) ? w - 1 : w + 1;
        if (nb >= 0 && nb < NW) {
          const ull* sp = slots + nb * 16;
          while ((unsigned)(ald(sp) >> 32) < (unsigned)k)
            __builtin_amdgcn_s_sleep(1);
        }
      }
      float htop = 0.f, dtop = 0.f, hbot = 0.f, dbot = 0.f;
      bool top = (a - 2 >= 0), bot5 = (a + 5 < NN), bot4 = (a + 4 < NN - 1);
      if (top)  { htop = cload(Hrd + (a - 2) * NN + j);
                  dtop = cload(Drd + (a - 2) * NN + j); }
      if (bot5)   hbot = cload(Hrd + (a + 5) * NN + j);
      if (bot4)   dbot = cload(Drd + (a + 4) * NN + j);
      if (top)  { Zs2[p][0][j] = ztreg[0] + htop; DB[0][j] = dtop; }
      if (bot5)   Zs2[p][HR + 3][j] = ztreg[HR + 3] + hbot;
      if (bot4)   DB[HR + 2][j] = dbot;
    }
    __syncthreads();

    // ---- part A: dt-independent stencil (overlaps reducer roundtrip)
    float dHdt[HR + 2];
#pragma unroll
    for (int ln = 0; ln < HR + 2; ++ln) {
      int i = a - 1 + ln;
      float v = 0.f;
      if (i > 0 && i < NN - 1 && j > 0 && j < NN - 1) {
        int li = ln + 1;
        float zc = Zs2[p][li][j];
        float zw = Zs2[p][li][j - 1];
        float ze = Zs2[p][li][j + 1];
        float zn = Zs2[p][li - 1][j];
        float zs_ = Zs2[p][li + 1][j];
        float d00 = DB[ln][j - 1], d01 = DB[ln][j];
        float d10 = DB[ln + 1][j - 1], d11 = DB[ln + 1][j];
        float qx0 = -(0.5f * (d00 + d10)) * (zc - zw) / 200.f;
        float qx1 = -(0.5f * (d01 + d11)) * (ze - zc) / 200.f;
        float qy0 = -(0.5f * (d00 + d01)) * (zc - zn) / 200.f;
        float qy1 = -(0.5f * (d10 + d11)) * (zs_ - zc) / 200.f;
        v = -((qx1 - qx0) / 200.f + (qy1 - qy0) / 200.f);
      }
      dHdt[ln] = v;
    }

    // ---- gated precip prefetch (exact-safe: do_upd => time - t_last >= 4)
    bool pre = (time - t_last) >= 4.0f;
    int idxn = min(idx + 1, 63);
    float pf[HR + 2];
    if (pre) {
      const float* prowN = precip + (size_t)idxn * MM;
#pragma unroll
      for (int ln = 0; ln < HR + 2; ++ln) {
        int i = a - 1 + ln;
        pf[ln] = (i >= 0 && i < NN) ? prowN[i * NN + j] : 0.f;
      }
    } else {
#pragma unroll
      for (int ln = 0; ln < HR + 2; ++ln) pf[ln] = 0.f;
    }
    asm volatile("" ::: "memory");   // pin prefetch issue before bcast poll

    // ---- get maxD (payload travels inside the flag; all waves poll)
    float maxD;
    if (k == 0) {
      maxD = 1e-10f;
    } else {
      ull b;
      while ((unsigned)((b = ald(bp)) >> 32) < (unsigned)k)
        __builtin_amdgcn_s_sleep(1);
      maxD = __uint_as_float((unsigned)b);
    }

    float dt = fminf(40000.0f / (2.7f * maxD), 1.0f);
    float tnew = time + dt;
    bool cap1 = (!s1) && (tnew >= 120.0f);
    bool cap2 = (!s2) && (tnew >= 160.0f);
    bool do_upd = (tnew - t_last) >= 5.0f;

    // ---- part B: finish H update, publishes, captures, smb refresh
    float hnxt[HR + 2];
#pragma unroll
    for (int ln = 0; ln < HR + 2; ++ln) {
      int i = a - 1 + ln;
      float hnew = 0.f;
      if (i >= 0 && i < NN) {
        if (i > 0 && i < NN - 1 && j > 0 && j < NN - 1)
          hnew = fmaxf(hcur[ln] + dt * (dHdt[ln] + smbreg[ln]), 0.f);
        float zsn = ztreg[ln + 1] + hnew;
        HnB[ln][j] = hnew;
        Zs2[p ^ 1][ln + 1][j] = zsn;
        if (i == a + 1 || i == a + 2) cstore(Hwr + i * NN + j, hnew);
        if (i >= a && i < a + HR) {
          int id = i * NN + j;
          if (cap1) out[id] = hnew;
          if (cap2) out[MM + id] = hnew;
        }
        if (do_upd)
          smbreg[ln] = pf[ln] - 0.5f * fmaxf(TmTs - 0.006f * zsn, 0.f);
      }
      hnxt[ln] = hnew;
    }
    __syncthreads();

    // ---- phase 2: new D rows a-1..a+3 (into DB slots 1..5) + block max
    float lmax = 0.f;
#pragma unroll
    for (int ln = 0; ln < HR + 1; ++ln) {
      int r = a - 1 + ln;
      if (r >= 0 && r < NN - 1 && j < NN - 1) {
        float h00 = HnB[ln][j], h01 = HnB[ln][j + 1];
        float h10 = HnB[ln + 1][j], h11 = HnB[ln + 1][j + 1];
        float z00 = Zs2[p ^ 1][ln + 1][j], z01 = Zs2[p ^ 1][ln + 1][j + 1];
        float z10 = Zs2[p ^ 1][ln + 2][j], z11 = Zs2[p ^ 1][ln + 2][j + 1];
        float havg = 0.25f * (((h00 + h11) + h01) + h10);
        float sx = 0.5f * ((z01 - z00) / 200.f + (z11 - z10) / 200.f);
        float sy = 0.5f * ((z10 - z00) / 200.f + (z11 - z01) / 200.f);
        float sn = sqrtf((sx * sx + sy * sy) + 1e-10f);
        float h2 = havg * havg;
        float h4 = h2 * h2;
        float h5 = h4 * havg;
        float d = CDIF * h5 * (sn * sn) + 1e-10f;
        DB[ln + 1][j] = d;
        if (r == a || r == a + 2) cstore(Dwr + r * NN + j, d);
        lmax = fmaxf(lmax, d);
      }
    }
    for (int off = 32; off; off >>= 1) lmax = fmaxf(lmax, __shfl_xor(lmax, off));
    if ((j & 63) == 0) wmax[j >> 6] = lmax;

    // ---- release: __syncthreads drains vmcnt (publishes at MALL), then flag
    __syncthreads();
    if (j == 0) {
      float bm = wmax[0];
#pragma unroll
      for (int q = 1; q < TPB / 64; ++q) bm = fmaxf(bm, wmax[q]);
      asto(myslot, ((ull)(unsigned)(k + 1) << 32) | __float_as_uint(bm));
    }

    // ---- bookkeeping
#pragma unroll
    for (int ln = 0; ln < HR + 2; ++ln) hcur[ln] = hnxt[ln];
    time = tnew;
    s1 = s1 || cap1;
    s2 = s2 || cap2;
    if (do_upd) { idx = idxn; t_last = tnew; }
  }

  // ---- final H (owned rows; hcur slot for row a+rr is rr+1)
#pragma unroll
  for (int rr = 0; rr < HR; ++rr)
    out[2 * MM + (a + rr) * NN + j] = hcur[rr + 1];
}

extern "C" void kernel_launch(void* const* d_in, const int* in_sizes, int n_in,
                              void* d_out, int out_size, void* d_ws, size_t ws_size,
                              hipStream_t stream) {
  const float* Zt = (const float*)d_in[0];
  const float* precip = (const float*)d_in[1];
  const float* Tm = (const float*)d_in[2];
  const float* Ts = (const float*)d_in[3];
  float* out = (float*)d_out;

  ull* bcast = (ull*)d_ws;                           // 64 lines @ 128 B
  ull* slots = (ull*)((char*)d_ws + 8192);           // 128 lines @ 128 B
  float* Ha = (float*)((char*)d_ws + 32768);
  float* Hb = Ha + MM;
  float* Da = Hb + MM;
  float* Db = Da + MM;

  hipMemsetAsync(d_ws, 0, 32768, stream);            // bcast + slots
  glacier_kernel<<<NW + 1, TPB, 0, stream>>>(Zt, precip, Tm, Ts, out,
                                             bcast, slots, Ha, Hb, Da, Db);
}

// Round 5
// 2388.348 us; speedup vs baseline: 15.8136x; 1.0807x over previous
//
#include <hip/hip_runtime.h>
#include <math.h>

// Glacier SIA stepper. 128 persistent worker blocks x 512 threads (no reducer).
// Per step: each block gathers all 128 {epoch,blockMaxD} slots directly
// (threads 0..127, one cacheline each) from a DEPTH-2 epoch-tagged ring,
// overlapping the gather RT with the halo-cload RT and dt-independent stencil
// rows. No threadfences: cross-block data moves via relaxed agent-scope
// atomics (MALL-coherent); __syncthreads' vmcnt drain orders publishes
// before the ring post.
//
// ws layout (bytes):
//   0     : ull ring[2][128] lines (stride 128 B) {epoch<<32 | blockMax bits}
//   32768 : float Ha[MM], Hb[MM], Da[MM], Db[MM] (published-row ping-pong)
// First 32768 B zeroed by captured hipMemsetAsync each call.

#define NN 512
#define MM (NN * NN)
#define NSTEPS 400
#define NW 128
#define HR 4
#define TPB 512

typedef unsigned long long ull;

__device__ __forceinline__ ull ald(const ull* p) {
  return __hip_atomic_load(p, __ATOMIC_RELAXED, __HIP_MEMORY_SCOPE_AGENT);
}
__device__ __forceinline__ void asto(ull* p, ull v) {
  __hip_atomic_store(p, v, __ATOMIC_RELAXED, __HIP_MEMORY_SCOPE_AGENT);
}
__device__ __forceinline__ float cload(const float* p) {
  return __hip_atomic_load(p, __ATOMIC_RELAXED, __HIP_MEMORY_SCOPE_AGENT);
}
__device__ __forceinline__ void cstore(float* p, float v) {
  __hip_atomic_store(p, v, __ATOMIC_RELAXED, __HIP_MEMORY_SCOPE_AGENT);
}

__global__ __launch_bounds__(TPB)
void glacier_kernel(const float* __restrict__ Zt,
                    const float* __restrict__ precip,
                    const float* __restrict__ Tm,
                    const float* __restrict__ Ts,
                    float* __restrict__ out,        // [3*MM]: H1, H2, H
                    ull* __restrict__ ring,         // [2][128] lines
                    float* __restrict__ Ha, float* __restrict__ Hb,
                    float* __restrict__ Da, float* __restrict__ Db) {
  __shared__ float Zs2[2][HR + 4][NN];
  __shared__ float DB[HR + 3][NN];
  __shared__ float HnB[HR + 2][NN];
  __shared__ float wmax[TPB / 64];
  __shared__ float gmax2[2];

  const int w = blockIdx.x;
  const int j = threadIdx.x;          // column
  const int lane = j & 63;
  const int a = w * HR;               // first owned row
  const float TmTs = Tm[0] + Ts[0];
  const double RG = 910.0 * 9.81;
  const float CDIF = (float)(1e-16 * RG * RG * RG);

  float ztreg[HR + 4];
  float hcur[HR + 2];
  float smbreg[HR + 2];

  // ---- prologue (no cross-block deps)
#pragma unroll
  for (int ls = 0; ls < HR + 4; ++ls) {
    int r = a - 2 + ls;
    float zt = (r >= 0 && r < NN) ? Zt[r * NN + j] : 0.f;
    ztreg[ls] = zt;
    Zs2[0][ls][j] = zt;               // H = 0
  }
#pragma unroll
  for (int ln = 0; ln < HR + 2; ++ln) {
    int r = a - 1 + ln;
    hcur[ln] = 0.f;
    float sm = 0.f;
    if (r >= 0 && r < NN) {
      float T = TmTs - 0.006f * ztreg[ln + 1];
      sm = precip[r * NN + j] - 0.5f * fmaxf(T, 0.f);
    }
    smbreg[ln] = sm;
  }
#pragma unroll
  for (int ld = 0; ld < HR + 3; ++ld) DB[ld][j] = 1e-10f;    // D(H=0) exactly
#pragma unroll
  for (int rr = 0; rr < HR; ++rr) {
    int id = (a + rr) * NN + j;
    out[id] = 0.f;
    out[MM + id] = 0.f;
  }
  __syncthreads();                    // prologue LDS visible to j+-1 readers

  float time = 0.f, t_last = 0.f;
  int idx = 0;
  bool s1 = false, s2 = false;

  for (int k = 0; k < NSTEPS; ++k) {
    if (time >= 200.0f) break;                  // uniform (dt identical)

    const int p = k & 1;
    float* Hwr = (k & 1) ? Ha : Hb;
    const float* Hrd = (k & 1) ? Hb : Ha;
    float* Dwr = (k & 1) ? Da : Db;
    const float* Drd = (k & 1) ? Db : Da;
    ull* ringp = ring + (size_t)(k & 1) * NW * 16;

    // ---- top-of-step samples (issue early; results used after part-A mid)
    bool pre = (time - t_last) >= 4.0f;         // exact-safe precip gate
    int idxn = min(idx + 1, 63);
    float pf[HR + 2];
    if (pre) {
      const float* prowN = precip + (size_t)idxn * MM;
#pragma unroll
      for (int ln = 0; ln < HR + 2; ++ln) {
        int i = a - 1 + ln;
        pf[ln] = (i >= 0 && i < NN) ? prowN[i * NN + j] : 0.f;
      }
    } else {
#pragma unroll
      for (int ln = 0; ln < HR + 2; ++ln) pf[ln] = 0.f;
    }
    const ull* np = nullptr; ull ns = 0;
    const ull* gp = nullptr; ull gv = 0;
    if (k > 0) {
      if (lane < 2) {                           // per-wave neighbor flag sample
        int nb = (lane == 0) ? w - 1 : w + 1;
        if (nb >= 0 && nb < NW) { np = ringp + nb * 16; ns = ald(np); }
      }
      if (j < NW) { gp = ringp + j * 16; gv = ald(gp); }   // gather sample
    }
    asm volatile("" ::: "memory");              // pin sample/prefetch issue

    // ---- part A mid: dHdt rows a..a+3 (halo-free; hides flag-sample RT)
    float dHdt[HR + 2];
#pragma unroll
    for (int ln = 1; ln <= HR; ++ln) {
      int i = a - 1 + ln;
      float v = 0.f;
      if (i > 0 && i < NN - 1 && j > 0 && j < NN - 1) {
        int li = ln + 1;
        float zc = Zs2[p][li][j];
        float zw = Zs2[p][li][j - 1];
        float ze = Zs2[p][li][j + 1];
        float zn = Zs2[p][li - 1][j];
        float zs_ = Zs2[p][li + 1][j];
        float d00 = DB[ln][j - 1], d01 = DB[ln][j];
        float d10 = DB[ln + 1][j - 1], d11 = DB[ln + 1][j];
        float qx0 = -(0.5f * (d00 + d10)) * (zc - zw) / 200.f;
        float qx1 = -(0.5f * (d01 + d11)) * (ze - zc) / 200.f;
        float qy0 = -(0.5f * (d00 + d01)) * (zc - zn) / 200.f;
        float qy1 = -(0.5f * (d10 + d11)) * (zs_ - zc) / 200.f;
        v = -((qx1 - qx0) / 200.f + (qy1 - qy0) / 200.f);
      }
      dHdt[ln] = v;
    }

    // ---- neighbor flag check -> issue halo cloads -> gather spin (RTs overlap)
    bool top = (a - 2 >= 0), bot5 = (a + 5 < NN), bot4 = (a + 4 < NN - 1);
    float htop = 0.f, dtop = 0.f, hbot = 0.f, dbot = 0.f;
    if (k > 0) {
      if (np) {
        while ((unsigned)(ns >> 32) < (unsigned)k) {
          __builtin_amdgcn_s_sleep(1);
          ns = ald(np);
        }
      }
      if (top)  { htop = cload(Hrd + (a - 2) * NN + j);
                  dtop = cload(Drd + (a - 2) * NN + j); }
      if (bot5)   hbot = cload(Hrd + (a + 5) * NN + j);
      if (bot4)   dbot = cload(Drd + (a + 4) * NN + j);
      if (j < NW) {                             // direct gather (waves 0,1)
        while ((unsigned)(gv >> 32) < (unsigned)k) {
          __builtin_amdgcn_s_sleep(1);
          gv = ald(gp);
        }
        float lm = __uint_as_float((unsigned)gv);
        for (int off = 32; off; off >>= 1) lm = fmaxf(lm, __shfl_xor(lm, off));
        if (lane == 0) gmax2[j >> 6] = lm;
      }
      // stage halos into LDS (cload results landed during the gather spin)
      if (top)  { Zs2[p][0][j] = ztreg[0] + htop; DB[0][j] = dtop; }
      if (bot5)   Zs2[p][HR + 3][j] = ztreg[HR + 3] + hbot;
      if (bot4)   DB[HR + 2][j] = dbot;
    }
    __syncthreads();                            // staged halos + gmax2 visible

    // ---- part A edges: dHdt rows a-1, a+4 (need staged halos)
#pragma unroll
    for (int ln = 0; ln <= HR + 1; ln += HR + 1) {
      int i = a - 1 + ln;
      float v = 0.f;
      if (i > 0 && i < NN - 1 && j > 0 && j < NN - 1) {
        int li = ln + 1;
        float zc = Zs2[p][li][j];
        float zw = Zs2[p][li][j - 1];
        float ze = Zs2[p][li][j + 1];
        float zn = Zs2[p][li - 1][j];
        float zs_ = Zs2[p][li + 1][j];
        float d00 = DB[ln][j - 1], d01 = DB[ln][j];
        float d10 = DB[ln + 1][j - 1], d11 = DB[ln + 1][j];
        float qx0 = -(0.5f * (d00 + d10)) * (zc - zw) / 200.f;
        float qx1 = -(0.5f * (d01 + d11)) * (ze - zc) / 200.f;
        float qy0 = -(0.5f * (d00 + d01)) * (zc - zn) / 200.f;
        float qy1 = -(0.5f * (d10 + d11)) * (zs_ - zc) / 200.f;
        v = -((qx1 - qx0) / 200.f + (qy1 - qy0) / 200.f);
      }
      dHdt[ln] = v;
    }

    float maxD = (k == 0) ? 1e-10f : fmaxf(gmax2[0], gmax2[1]);
    float dt = fminf(40000.0f / (2.7f * maxD), 1.0f);
    float tnew = time + dt;
    bool cap1 = (!s1) && (tnew >= 120.0f);
    bool cap2 = (!s2) && (tnew >= 160.0f);
    bool do_upd = (tnew - t_last) >= 5.0f;

    // ---- part B: H update, publishes, captures, smb refresh
    float hnxt[HR + 2];
#pragma unroll
    for (int ln = 0; ln < HR + 2; ++ln) {
      int i = a - 1 + ln;
      float hnew = 0.f;
      if (i >= 0 && i < NN) {
        if (i > 0 && i < NN - 1 && j > 0 && j < NN - 1)
          hnew = fmaxf(hcur[ln] + dt * (dHdt[ln] + smbreg[ln]), 0.f);
        float zsn = ztreg[ln + 1] + hnew;
        HnB[ln][j] = hnew;
        Zs2[p ^ 1][ln + 1][j] = zsn;
        if (i == a + 1 || i == a + 2) cstore(Hwr + i * NN + j, hnew);
        if (i >= a && i < a + HR) {
          int id = i * NN + j;
          if (cap1) out[id] = hnew;
          if (cap2) out[MM + id] = hnew;
        }
        if (do_upd)
          smbreg[ln] = pf[ln] - 0.5f * fmaxf(TmTs - 0.006f * zsn, 0.f);
      }
      hnxt[ln] = hnew;
    }
    __syncthreads();

    // ---- phase 2: new D rows a-1..a+3 (into DB slots 1..5) + block max
    float lmax = 0.f;
#pragma unroll
    for (int ln = 0; ln < HR + 1; ++ln) {
      int r = a - 1 + ln;
      if (r >= 0 && r < NN - 1 && j < NN - 1) {
        float h00 = HnB[ln][j], h01 = HnB[ln][j + 1];
        float h10 = HnB[ln + 1][j], h11 = HnB[ln + 1][j + 1];
        float z00 = Zs2[p ^ 1][ln + 1][j], z01 = Zs2[p ^ 1][ln + 1][j + 1];
        float z10 = Zs2[p ^ 1][ln + 2][j], z11 = Zs2[p ^ 1][ln + 2][j + 1];
        float havg = 0.25f * (((h00 + h11) + h01) + h10);
        float sx = 0.5f * ((z01 - z00) / 200.f + (z11 - z10) / 200.f);
        float sy = 0.5f * ((z10 - z00) / 200.f + (z11 - z01) / 200.f);
        float sn = sqrtf((sx * sx + sy * sy) + 1e-10f);
        float h2 = havg * havg;
        float h4 = h2 * h2;
        float h5 = h4 * havg;
        float d = CDIF * h5 * (sn * sn) + 1e-10f;
        DB[ln + 1][j] = d;
        if (r == a || r == a + 2) cstore(Dwr + r * NN + j, d);
        lmax = fmaxf(lmax, d);
      }
    }
    for (int off = 32; off; off >>= 1) lmax = fmaxf(lmax, __shfl_xor(lmax, off));
    if (lane == 0) wmax[j >> 6] = lmax;

    // ---- release: syncthreads drains publishes (vmcnt), then post ring slot
    __syncthreads();
    if (j == 0) {
      float bm = wmax[0];
#pragma unroll
      for (int q = 1; q < TPB / 64; ++q) bm = fmaxf(bm, wmax[q]);
      asto(ring + (size_t)((k + 1) & 1) * NW * 16 + w * 16,
           ((ull)(unsigned)(k + 1) << 32) | __float_as_uint(bm));
    }

    // ---- bookkeeping
#pragma unroll
    for (int ln = 0; ln < HR + 2; ++ln) hcur[ln] = hnxt[ln];
    time = tnew;
    s1 = s1 || cap1;
    s2 = s2 || cap2;
    if (do_upd) { idx = idxn; t_last = tnew; }
  }

  // ---- final H (owned rows; hcur slot for row a+rr is rr+1)
#pragma unroll
  for (int rr = 0; rr < HR; ++rr)
    out[2 * MM + (a + rr) * NN + j] = hcur[rr + 1];
}

extern "C" void kernel_launch(void* const* d_in, const int* in_sizes, int n_in,
                              void* d_out, int out_size, void* d_ws, size_t ws_size,
                              hipStream_t stream) {
  const float* Zt = (const float*)d_in[0];
  const float* precip = (const float*)d_in[1];
  const float* Tm = (const float*)d_in[2];
  const float* Ts = (const float*)d_in[3];
  float* out = (float*)d_out;

  ull* ring = (ull*)d_ws;                            // 2*128 lines @ 128 B
  float* Ha = (float*)((char*)d_ws + 32768);
  float* Hb = Ha + MM;
  float* Da = Hb + MM;
  float* Db = Da + MM;

  hipMemsetAsync(d_ws, 0, 32768, stream);            // ring tags -> 0
  glacier_kernel<<<NW, TPB, 0, stream>>>(Zt, precip, Tm, Ts, out,
                                         ring, Ha, Hb, Da, Db);
}